// Round 5
// baseline (1768.117 us; speedup 1.0000x reference)
//
#include <hip/hip_runtime.h>

// ============================================================================
// MYLSTM: functional-basis LSTM, T=49, BATCH=2048, UNITS=DIM=256, QN=9.
//
// Round 5 vs round 4 (fix utilization / spill / store pattern):
//  - rec_k: 256 wgs x 1024 thr, 8 batch rows per wg (full machine; was 128
//    wgs = half idle). A-rows 8..15 zero; output stores predicated quad<2.
//  - amdgpu_waves_per_eu(4,4): register budget pinned to 128 VGPR so the
//    backend can't spill to chase 8 waves/EU (r4: VGPR=64, WRITE 151MB vs
//    51MB legit => ~100MB scratch/partial-line writeback).
//  - S stores via double-buffered LDS bounce -> one coalesced full-line nt
//    store per thread, issued after the barrier, hidden under next gate GEMM.
//  - proj_k: nt stores for out (103MB write-once; keep UP_t/S in L2).
// Kept: h not recurrent (proj hoisted out of serial loop); K=512 fused gate
// GEMM; gate-per-lane in-register elementwise; 1 barrier/step.
// ============================================================================

typedef unsigned short u16;
typedef unsigned int u32;
typedef __attribute__((ext_vector_type(8))) short bf16x8;
typedef __attribute__((ext_vector_type(4))) float f32x4;
typedef __attribute__((ext_vector_type(2))) float f32x2;

#define T_STEPS 49
#define OUT_ROW 12544 // 49*256

__device__ __forceinline__ u16 f2b(float f) {
  u32 u = __float_as_uint(f);
  u += 0x7fffu + ((u >> 16) & 1u); // RNE
  return (u16)(u >> 16);
}
__device__ __forceinline__ float b2f(u16 h) { return __uint_as_float(((u32)h) << 16); }
__device__ __forceinline__ float sigm(float z) { return 1.0f / (1.0f + __expf(-z)); }
__device__ __forceinline__ float tanh_f(float z) {
  float e = __expf(-2.0f * fabsf(z));
  float r = (1.0f - e) / (1.0f + e); // overflow-safe: e->0 => 1
  return __builtin_copysignf(r, z);
}

// ---------------------------------------------------------------------------
// Pack fused weights: WP[n][k], n=g*256+u (g in {f,i,c,o}), k=0..511 over
// cat=[c|x]. WP[n*512+k] = W_g[k][u].
__global__ void pack_w(const float* __restrict__ Wf, const float* __restrict__ Wi,
                       const float* __restrict__ Wc, const float* __restrict__ Wo,
                       u16* __restrict__ WP) {
  int n = blockIdx.x, k = threadIdx.x;
  int g = n >> 8, u = n & 255;
  const float* W = (g == 0) ? Wf : (g == 1) ? Wi : (g == 2) ? Wc : Wo;
  WP[n * 512 + k] = f2b(W[k * 256 + u]);
  WP[n * 512 + 256 + k] = f2b(W[(256 + k) * 256 + u]);
}

// ---------------------------------------------------------------------------
// U pack: UP[t][jp][j] = sum_q Q[j*2304 + jp*9 + q] * B(t,q), bf16.
__global__ void pack_u(const float* __restrict__ Q, u16* __restrict__ UP) {
  int bx = blockIdx.x;
  int t = bx >> 8, jp = bx & 255, j = threadIdx.x;
  const float* q = Q + j * 2304 + jp * 9;
  float tv = (float)t / 48.0f;
  float acc = q[0];
  const float SQ2 = 1.41421356237f;
#pragma unroll
  for (int i = 1; i <= 4; ++i) {
    float ang = 6.283185307179586f * (float)i * tv;
    acc += SQ2 * (sinf(ang) * q[2 * i - 1] + cosf(ang) * q[2 * i]);
  }
  UP[t * 65536 + jp * 256 + j] = f2b(acc);
}

// ---------------------------------------------------------------------------
// Recurrent kernel: 256 wgs x 1024 thr (16 waves). wg owns batch rows b0..b0+7.
// Per step: Z[8][1024] = [c|x_t] @ WP (K=512, A rows 8..15 zero), elementwise
// in-register, cn -> next A-buf (LDS), s -> sB (LDS) -> coalesced nt store.
__global__ __launch_bounds__(1024)
__attribute__((amdgpu_waves_per_eu(4, 4)))
void rec_k(const u16* __restrict__ WP, const float* __restrict__ x,
           u16* __restrict__ S) {
  __shared__ u16 aB[2][16 * 512]; // 2 x 16KB, byte col ^= (row&7)<<4 swizzle
  __shared__ u16 sB[2][8 * 256];  // s bounce, double-buffered
  int tid = threadIdx.x;
  int b0 = blockIdx.x * 8;
  int w = tid >> 6, l = tid & 63, lane15 = l & 15, quad = l >> 4;
  int u_own = w * 16 + lane15; // this lane's unit (all 4 gates)

  // zero both A buffers (rows 8..15 must stay zero forever)
  for (int i = tid; i < 8192; i += 1024) ((u32*)aB)[i] = 0u;
  // stage x(t=0) rows 0..7 into aB[0] x-part
  int xr = tid >> 7, xc = (tid & 127) * 2; // staging row / col (2 f32 per thr)
  {
    const f32x2 v = *(const f32x2*)&x[((size_t)(b0 + xr) * T_STEPS + 0) * 256 + xc];
    u16 tmp[2] = {f2b(v.x), f2b(v.y)};
    int bxc = 512 + xc * 2;
    *(u32*)((char*)&aB[0][0] + xr * 1024 + (bxc ^ ((xr & 7) << 4))) = *(u32*)tmp;
  }
  __syncthreads();

  float creg[4] = {0.f, 0.f, 0.f, 0.f};
  const u16* bp0 = WP + ((size_t)(0 * 256 + u_own)) * 512 + quad * 8;
  const u16* bp1 = WP + ((size_t)(1 * 256 + u_own)) * 512 + quad * 8;
  const u16* bp2 = WP + ((size_t)(2 * 256 + u_own)) * 512 + quad * 8;
  const u16* bp3 = WP + ((size_t)(3 * 256 + u_own)) * 512 + quad * 8;

  int p = 0;
#pragma unroll 1
  for (int t = 0; t < T_STEPS; ++t) {
    // issue next-step x load early (hides HBM latency under gate GEMM)
    f32x2 xv = {0.f, 0.f};
    if (t + 1 < T_STEPS)
      xv = __builtin_nontemporal_load(
          (const f32x2*)&x[((size_t)(b0 + xr) * T_STEPS + (t + 1)) * 256 + xc]);

    // ---- gate GEMM: 4 gate tiles, K=512 (16 k-chunks of 32)
    f32x4 a0 = {0.f, 0.f, 0.f, 0.f}, a1 = a0, a2 = a0, a3 = a0;
    const char* ab = (const char*)&aB[p][0];
#pragma unroll
    for (int ks = 0; ks < 16; ++ks) {
      bf16x8 af = *(const bf16x8*)(ab + lane15 * 1024 +
                                   ((ks * 64 + quad * 16) ^ ((lane15 & 7) << 4)));
      a0 = __builtin_amdgcn_mfma_f32_16x16x32_bf16(af, *(const bf16x8*)(bp0 + ks * 32), a0, 0, 0, 0);
      a1 = __builtin_amdgcn_mfma_f32_16x16x32_bf16(af, *(const bf16x8*)(bp1 + ks * 32), a1, 0, 0, 0);
      a2 = __builtin_amdgcn_mfma_f32_16x16x32_bf16(af, *(const bf16x8*)(bp2 + ks * 32), a2, 0, 0, 0);
      a3 = __builtin_amdgcn_mfma_f32_16x16x32_bf16(af, *(const bf16x8*)(bp3 + ks * 32), a3, 0, 0, 0);
    }

    // ---- elementwise in-register (lane: rows quad*4..+3, unit u_own;
    //      rows >= 8 compute harmless junk and store nothing)
    char* abn = (char*)&aB[p ^ 1][0];
#pragma unroll
    for (int i = 0; i < 4; ++i) {
      int r = quad * 4 + i;
      float f = sigm(a0[i]), ii = sigm(a1[i]), gg = sigm(a2[i]), o = tanh_f(a3[i]);
      float cn = ii * gg + f * creg[i];
      creg[i] = cn;
      float s = o * tanh_f(cn);
      if (quad < 2) {
        if (t + 1 < T_STEPS)
          *(u16*)(abn + r * 1024 + ((u_own * 2) ^ ((r & 7) << 4))) = f2b(cn);
        sB[p][r * 256 + u_own] = f2b(s);
      }
    }

    // ---- write staged x_{t+1} into next A-buf
    if (t + 1 < T_STEPS) {
      u16 tmp[2] = {f2b(xv.x), f2b(xv.y)};
      int bxc = 512 + xc * 2;
      *(u32*)(abn + xr * 1024 + (bxc ^ ((xr & 7) << 4))) = *(u32*)tmp;
    }
    __syncthreads();
    // ---- coalesced full-line S store from sB[p] (hidden under next GEMM;
    //      sB double-buffered so next step's writes can't race this read)
    {
      u32 v2 = *(const u32*)&sB[p][xr * 256 + xc]; // xr/xc: 8 rows x 128 u32
      __builtin_nontemporal_store(
          v2, (u32*)&S[((size_t)t * 2048 + b0 + xr) * 256 + xc]);
    }
    p ^= 1;
  }
}

// ---------------------------------------------------------------------------
// Proj kernel: h = tanh(S_t @ U_t), per t: M=2048, N=256, K=256.
// grid 49*32 wgs x 512 thr (8 waves); bx -> (t, mtile of 64 rows).
// t-major block order => 32 consecutive wgs share UP_t via L2.
__global__ __launch_bounds__(512) void proj_k(const u16* __restrict__ S,
                                              const u16* __restrict__ UP,
                                              float* __restrict__ out) {
  int bx = blockIdx.x;
  int t = bx >> 5, mt = bx & 31;
  int m0 = mt * 64;
  int tid = threadIdx.x;
  int w = tid >> 6, l = tid & 63, lane15 = l & 15, quad = l >> 4;
  const u16* Sbase = S + ((size_t)t * 2048 + m0) * 256;
  const u16* Ubase = UP + (size_t)t * 65536;
#pragma unroll
  for (int rtp = 0; rtp < 2; ++rtp) {
    bf16x8 af[2][8];
#pragma unroll
    for (int h = 0; h < 2; ++h)
#pragma unroll
      for (int ks = 0; ks < 8; ++ks)
        af[h][ks] = *(const bf16x8*)(Sbase + (rtp * 32 + h * 16 + lane15) * 256 +
                                     ks * 32 + quad * 8);
#pragma unroll
    for (int ct = 0; ct < 2; ++ct) {
      int col = w * 32 + ct * 16 + lane15;
      const u16* up = Ubase + col * 256 + quad * 8;
      bf16x8 bf[8];
#pragma unroll
      for (int ks = 0; ks < 8; ++ks) bf[ks] = *(const bf16x8*)(up + ks * 32);
#pragma unroll
      for (int h = 0; h < 2; ++h) {
        f32x4 acc = {0.f, 0.f, 0.f, 0.f};
#pragma unroll
        for (int ks = 0; ks < 8; ++ks)
          acc = __builtin_amdgcn_mfma_f32_16x16x32_bf16(af[h][ks], bf[ks], acc, 0, 0, 0);
#pragma unroll
        for (int i = 0; i < 4; ++i) {
          int b = m0 + rtp * 32 + h * 16 + quad * 4 + i;
          __builtin_nontemporal_store(
              tanh_f(acc[i]), &out[(size_t)b * OUT_ROW + t * 256 + col]);
        }
      }
    }
  }
}

// ---------------------------------------------------------------------------
extern "C" void kernel_launch(void* const* d_in, const int* in_sizes, int n_in,
                              void* d_out, int out_size, void* d_ws, size_t ws_size,
                              hipStream_t stream) {
  const float* x = (const float*)d_in[0];
  const float* Wf = (const float*)d_in[1];
  const float* Wi = (const float*)d_in[2];
  const float* Wc = (const float*)d_in[3];
  const float* Wo = (const float*)d_in[4];
  const float* Q = (const float*)d_in[5];
  float* out = (float*)d_out;

  char* p = (char*)d_ws;
  u16* WP = (u16*)p;  p += (size_t)1024 * 512 * 2;        // 1 MB fused gate weights
  u16* UP = (u16*)p;  p += (size_t)49 * 256 * 256 * 2;    // 6.13 MB
  u16* Sb = (u16*)p;  p += (size_t)49 * 2048 * 256 * 2;   // 51.4 MB s-values
  (void)ws_size;

  pack_w<<<dim3(1024), dim3(256), 0, stream>>>(Wf, Wi, Wc, Wo, WP);
  pack_u<<<dim3(49 * 256), dim3(256), 0, stream>>>(Q, UP);
  rec_k<<<dim3(256), dim3(1024), 0, stream>>>(WP, x, Sb);
  proj_k<<<dim3(49 * 32), dim3(512), 0, stream>>>(Sb, UP, out);
}